// Round 6
// baseline (75.656 us; speedup 1.0000x reference)
//
#include <hip/hip_runtime.h>
#include <math.h>

#define NSAMP 128
#define NTOT  512            // NCELLS * NP
#define NJQ   8              // j-chunks per row
#define JCH   (NTOT / NJQ)   // 64
#define ITILE 64             // i-rows per block (512 threads = 64 i x 8 jq)

#define TBL_N    4096
#define TBL_SIZE (TBL_N + 2)     // entries 0..4097 (guard)
#define TBL_H    0.0048828125f   // 20/4096, exact in fp32
#define TBL_SCALE 204.8f         // 4096/20

// Packed nearest-neighbor table: u32 = bf16(w) << 16 | bf16(i0e), at d_k = k*h.
__device__ unsigned g_tbl[TBL_SIZE];

// ---------------- accurate math for the table fill (cost irrelevant) -------

template <int N>
__device__ __forceinline__ float horner(float x, const float (&c)[N]) {
  float p = 0.0f;
#pragma unroll
  for (int i = 0; i < N; ++i) p = __fadd_rn(__fmul_rn(p, x), c[i]);
  return p;
}

template <int N>
__device__ __forceinline__ float chbevl(float x, const float (&c)[N]) {
  float b0 = 0.0f, b1 = 0.0f, b2 = 0.0f;
#pragma unroll
  for (int i = 0; i < N; ++i) {
    b2 = b1;
    b1 = b0;
    b0 = __fadd_rn(__fsub_rn(__fmul_rn(x, b1), b2), c[i]);
  }
  return __fmul_rn(0.5f, __fsub_rn(b0, b2));
}

__device__ __forceinline__ float erfc_xla(float x) {
  const float kErfT[7] = {
      +7.853861353153693E-5f, -8.010193625184903E-4f, +5.188327685732524E-3f,
      -2.685381193529856E-2f, +1.128358514861418E-1f, -3.761262582423300E-1f,
      +1.128379165726710E+0f};
  const float kP[9] = {
      +2.326819970068386E-2f, -1.387039388740657E-1f, +3.687424674597105E-1f,
      -5.824733027278666E-1f, +6.210004621745983E-1f, -4.944515323274145E-1f,
      +3.404879937665872E-1f, -2.741127028184656E-1f, +5.638259427386472E-1f};
  const float kR[8] = {
      -1.047766399936249E+1f, +1.297719955372516E+1f, -7.495518717768503E+0f,
      +2.921019019210786E+0f, -1.015265279202700E+0f, +4.218463358204948E-1f,
      -2.820767439740514E-1f, +5.641895067754075E-1f};

  float ax = fabsf(x);
  float x2 = __fmul_rn(x, x);
  float erf_small = __fmul_rn(x, horner(x2, kErfT));
  float erf_based = __fsub_rn(1.0f, erf_small);
  float z = expf(-x2);
  float q = __fdiv_rn(1.0f, ax);
  float y = __fmul_rn(q, q);
  float p = (ax < 2.0f) ? horner(y, kP) : horner(y, kR);
  float r = __fmul_rn(__fmul_rn(z, q), p);
  float ec = (x < 0.0f) ? __fsub_rn(2.0f, r) : r;
  return (ax < 1.0f) ? erf_based : ec;
}

__device__ __forceinline__ float i0e_xla(float x) {
  const float kA[18] = {
      -1.30002500998624804212E-8f, 6.04699502254191894932E-8f,
      -2.67079385394061173391E-7f, 1.11738753912010371815E-6f,
      -4.41673835845875056359E-6f, 1.64484480707288970893E-5f,
      -5.75419501008210370398E-5f, 1.88502885095841655729E-4f,
      -5.76375574538582365885E-4f, 1.63947561694133579842E-3f,
      -4.32430999505057594430E-3f, 1.05464603945949983183E-2f,
      -2.37374148058994688156E-2f, 4.93052842396707084878E-2f,
      -9.49010970480476444210E-2f, 1.71620901522208775349E-1f,
      -3.04682672343198398683E-1f, 6.76795274409476084995E-1f};
  const float kB[7] = {
      3.39623202570838634515E-9f, 2.26666899049817806459E-8f,
      2.04891858946906374183E-7f, 2.89137052083475648297E-6f,
      6.88975834691682398426E-5f, 3.36911647825569408990E-3f,
      8.04490411014108831608E-1f};
  float le8 = chbevl(__fsub_rn(__fmul_rn(0.5f, x), 2.0f), kA);
  float arg = __fsub_rn(__fdiv_rn(32.0f, x), 2.0f);
  float gt8 = __fdiv_rn(chbevl(arg, kB), __fsqrt_rn(x));
  return (x <= 8.0f) ? le8 : gt8;
}

__device__ __forceinline__ float window_ref(float d) {
  return 1.0f - 0.5f * erfc_xla(2.0f * d - 3.0f);
}

__device__ __forceinline__ unsigned to_bf16_rne(float x) {
  unsigned u = __float_as_uint(x);
  unsigned lsb = (u >> 16) & 1u;
  return (u + 0x7FFFu + lsb) >> 16;
}

// --------------------------- table fill kernel -----------------------------

__global__ __launch_bounds__(256) void fill_tbl_kernel() {
  int k = blockIdx.x * 256 + threadIdx.x;
  if (k >= TBL_SIZE) return;
  float d = fminf((float)k * TBL_H, 20.0f);
  float w = window_ref(d);
  float io = (k == 0) ? 1.0f : i0e_xla(d);
  g_tbl[k] = (to_bf16_rne(w) << 16) | to_bf16_rne(io);
}

// ------------------------------ main kernel --------------------------------

// Padded coordinate layout: chunk q (64 floats) starts at word 68*q so the 8
// per-wave float4 broadcasts land on different bank-quads.
#define RSP(j) ((j) + (((j) >> 6) << 2))
#define RSP_SIZE (NTOT + 4 * (NJQ - 1))  // 540

__global__ __launch_bounds__(512) void fmm_window_kernel(
    const float* __restrict__ R, const float* __restrict__ stdp,
    const float* __restrict__ biasp, float* __restrict__ out) {
  __shared__ unsigned T[TBL_SIZE];  // 16.4 KB, random b32 gather (~2-way free)
  __shared__ float Rs[RSP_SIZE];    // 2.2 KB

  const int tid = threadIdx.x;
  const int bid = blockIdx.x;
  const int s = bid >> 3;      // sample
  const int itile = bid & 7;   // 64-row tile of i

  for (int k = tid; k < TBL_SIZE; k += 512) T[k] = g_tbl[k];
  Rs[RSP(tid)] = R[s * NTOT + tid];
  __syncthreads();

  const int il = tid >> 3;     // local i (0..63)
  const int jq = tid & 7;      // j-chunk (0..7)
  const int i = itile * ITILE + il;
  const float ri = Rs[RSP(i)];

  float a0 = 0.0f, a1 = 0.0f, a2 = 0.0f, a3 = 0.0f;

  const int jw = jq * 68;      // padded word base of this j-chunk
#pragma unroll 4
  for (int jj = 0; jj < JCH; jj += 4) {
    const float4 rj = *reinterpret_cast<const float4*>(&Rs[jw + jj]);
#pragma unroll
    for (int u = 0; u < 4; ++u) {
      const float rjv = (u == 0) ? rj.x : (u == 1) ? rj.y : (u == 2) ? rj.z : rj.w;
      const float t = rjv - ri;
      // nearest-neighbor index: k = round(|t| * SCALE)
      const float x = fmaf(fabsf(t), TBL_SCALE, 0.5f);
      const int k = (int)x;
      const unsigned tv = T[k];                   // one ds_read_b32
      const float io = __uint_as_float(tv << 16);
      float w = __uint_as_float(tv & 0xFFFF0000u);
      // t == 0: diagonal (ref excludes) or exact collision (ref -> inf);
      // we must stay finite: zero the weight, clamp the rsq argument.
      w = (t == 0.0f) ? 0.0f : w;
      const float dd = fabsf(t) + 1e-30f;
      const float r = __builtin_amdgcn_rsqf(dd);  // 1/sqrt(d)
      const float inv = r * r;                    // 1/d (2-3 ulp, fine)
      const float wi = w * inv;
      a0 = fmaf(w, inv, a0);
      a1 = fmaf(w, r, a1);
      a2 = fmaf(wi, inv, a2);
      a3 = fmaf(w, io, a3);
    }
  }

  // combine the 8 j-chunks: lanes (8k..8k+7) hold the same i
  a0 += __shfl_xor(a0, 1); a0 += __shfl_xor(a0, 2); a0 += __shfl_xor(a0, 4);
  a1 += __shfl_xor(a1, 1); a1 += __shfl_xor(a1, 2); a1 += __shfl_xor(a1, 4);
  a2 += __shfl_xor(a2, 1); a2 += __shfl_xor(a2, 2); a2 += __shfl_xor(a2, 4);
  a3 += __shfl_xor(a3, 1); a3 += __shfl_xor(a3, 2); a3 += __shfl_xor(a3, 4);

  if (jq == 0) {
    float* o = out + ((size_t)(s * NTOT + i)) * 4;
    const float nm1 = 511.0f;  // N - 1
    o[0] = fabsf(stdp[0]) * (a0 - nm1 * biasp[0]);
    o[1] = fabsf(stdp[1]) * (a1 - nm1 * biasp[1]);
    o[2] = fabsf(stdp[2]) * (a2 - nm1 * biasp[2]);
    o[3] = fabsf(stdp[3]) * (a3 - nm1 * biasp[3]);
  }
}

extern "C" void kernel_launch(void* const* d_in, const int* in_sizes, int n_in,
                              void* d_out, int out_size, void* d_ws, size_t ws_size,
                              hipStream_t stream) {
  const float* R = (const float*)d_in[0];
  const float* stdp = (const float*)d_in[1];
  const float* biasp = (const float*)d_in[2];
  float* out = (float*)d_out;

  hipLaunchKernelGGL(fill_tbl_kernel, dim3((TBL_SIZE + 255) / 256), dim3(256),
                     0, stream);
  hipLaunchKernelGGL(fmm_window_kernel, dim3(NSAMP * (NTOT / ITILE)), dim3(512),
                     0, stream, R, stdp, biasp, out);
}

// Round 7
// 73.263 us; speedup vs baseline: 1.0327x; 1.0327x over previous
//
#include <hip/hip_runtime.h>
#include <math.h>

#define NSAMP 128
#define NTOT  512            // NCELLS * NP
#define NJQ   8              // j-chunks per row
#define JCH   (NTOT / NJQ)   // 64
#define ITILE 64             // i-rows per block (512 threads = 64 i x 8 jq)

#define TBL_N    4096
#define TBL_SIZE (TBL_N + 2)     // entries 0..4097 (guard)
#define TBL_H    0.0048828125f   // 20/4096, exact in fp32
#define TBL_SCALE 204.8f         // 4096/20

// Packed nearest-neighbor table: u32 = bf16(i0e) << 16 | bf16(w), at d_k = k*h.
// Bin 0 stores w = 0 so diagonal / exact-collision pairs contribute exactly 0
// (reference -> excluded or inf; we must stay finite & NaN-free).
__device__ unsigned g_tbl[TBL_SIZE];

// ---------------- accurate math for the table fill (cost irrelevant) -------

template <int N>
__device__ __forceinline__ float horner(float x, const float (&c)[N]) {
  float p = 0.0f;
#pragma unroll
  for (int i = 0; i < N; ++i) p = __fadd_rn(__fmul_rn(p, x), c[i]);
  return p;
}

template <int N>
__device__ __forceinline__ float chbevl(float x, const float (&c)[N]) {
  float b0 = 0.0f, b1 = 0.0f, b2 = 0.0f;
#pragma unroll
  for (int i = 0; i < N; ++i) {
    b2 = b1;
    b1 = b0;
    b0 = __fadd_rn(__fsub_rn(__fmul_rn(x, b1), b2), c[i]);
  }
  return __fmul_rn(0.5f, __fsub_rn(b0, b2));
}

__device__ __forceinline__ float erfc_xla(float x) {
  const float kErfT[7] = {
      +7.853861353153693E-5f, -8.010193625184903E-4f, +5.188327685732524E-3f,
      -2.685381193529856E-2f, +1.128358514861418E-1f, -3.761262582423300E-1f,
      +1.128379165726710E+0f};
  const float kP[9] = {
      +2.326819970068386E-2f, -1.387039388740657E-1f, +3.687424674597105E-1f,
      -5.824733027278666E-1f, +6.210004621745983E-1f, -4.944515323274145E-1f,
      +3.404879937665872E-1f, -2.741127028184656E-1f, +5.638259427386472E-1f};
  const float kR[8] = {
      -1.047766399936249E+1f, +1.297719955372516E+1f, -7.495518717768503E+0f,
      +2.921019019210786E+0f, -1.015265279202700E+0f, +4.218463358204948E-1f,
      -2.820767439740514E-1f, +5.641895067754075E-1f};

  float ax = fabsf(x);
  float x2 = __fmul_rn(x, x);
  float erf_small = __fmul_rn(x, horner(x2, kErfT));
  float erf_based = __fsub_rn(1.0f, erf_small);
  float z = expf(-x2);
  float q = __fdiv_rn(1.0f, ax);
  float y = __fmul_rn(q, q);
  float p = (ax < 2.0f) ? horner(y, kP) : horner(y, kR);
  float r = __fmul_rn(__fmul_rn(z, q), p);
  float ec = (x < 0.0f) ? __fsub_rn(2.0f, r) : r;
  return (ax < 1.0f) ? erf_based : ec;
}

__device__ __forceinline__ float i0e_xla(float x) {
  const float kA[18] = {
      -1.30002500998624804212E-8f, 6.04699502254191894932E-8f,
      -2.67079385394061173391E-7f, 1.11738753912010371815E-6f,
      -4.41673835845875056359E-6f, 1.64484480707288970893E-5f,
      -5.75419501008210370398E-5f, 1.88502885095841655729E-4f,
      -5.76375574538582365885E-4f, 1.63947561694133579842E-3f,
      -4.32430999505057594430E-3f, 1.05464603945949983183E-2f,
      -2.37374148058994688156E-2f, 4.93052842396707084878E-2f,
      -9.49010970480476444210E-2f, 1.71620901522208775349E-1f,
      -3.04682672343198398683E-1f, 6.76795274409476084995E-1f};
  const float kB[7] = {
      3.39623202570838634515E-9f, 2.26666899049817806459E-8f,
      2.04891858946906374183E-7f, 2.89137052083475648297E-6f,
      6.88975834691682398426E-5f, 3.36911647825569408990E-3f,
      8.04490411014108831608E-1f};
  float le8 = chbevl(__fsub_rn(__fmul_rn(0.5f, x), 2.0f), kA);
  float arg = __fsub_rn(__fdiv_rn(32.0f, x), 2.0f);
  float gt8 = __fdiv_rn(chbevl(arg, kB), __fsqrt_rn(x));
  return (x <= 8.0f) ? le8 : gt8;
}

__device__ __forceinline__ float window_ref(float d) {
  return 1.0f - 0.5f * erfc_xla(2.0f * d - 3.0f);
}

__device__ __forceinline__ unsigned to_bf16_rne(float x) {
  unsigned u = __float_as_uint(x);
  unsigned lsb = (u >> 16) & 1u;
  return (u + 0x7FFFu + lsb) >> 16;
}

// --------------------------- table fill kernel -----------------------------

__global__ __launch_bounds__(256) void fill_tbl_kernel() {
  int k = blockIdx.x * 256 + threadIdx.x;
  if (k >= TBL_SIZE) return;
  float d = fminf((float)k * TBL_H, 20.0f);
  float w = (k == 0) ? 0.0f : window_ref(d);   // bin 0: zero weight
  float io = (k == 0) ? 1.0f : i0e_xla(d);
  // io in HIGH 16 bits (read back with 0 ops, <=0.8% mantissa noise),
  // w in LOW 16 bits (read back exactly via << 16).
  g_tbl[k] = (to_bf16_rne(io) << 16) | to_bf16_rne(w);
}

// ------------------------------ main kernel --------------------------------

// Padded coordinate layout: chunk q (64 floats) starts at word 68*q so the 8
// per-wave float4 broadcasts land on different bank-quads.
#define RSP(j) ((j) + (((j) >> 6) << 2))
#define RSP_SIZE (NTOT + 4 * (NJQ - 1))  // 540

__global__ __launch_bounds__(512) void fmm_window_kernel(
    const float* __restrict__ R, const float* __restrict__ stdp,
    const float* __restrict__ biasp, float* __restrict__ out) {
  __shared__ unsigned T[TBL_SIZE];  // 16.4 KB
  __shared__ float Rs[RSP_SIZE];    // 2.2 KB

  const int tid = threadIdx.x;
  const int bid = blockIdx.x;
  const int s = bid >> 3;      // sample
  const int itile = bid & 7;   // 64-row tile of i

  for (int k = tid; k < TBL_SIZE; k += 512) T[k] = g_tbl[k];
  Rs[RSP(tid)] = R[s * NTOT + tid];
  __syncthreads();

  const int il = tid >> 3;     // local i (0..63)
  const int jq = tid & 7;      // j-chunk (0..7)
  const int i = itile * ITILE + il;
  const float ri = Rs[RSP(i)];

  float a0 = 0.0f, a1 = 0.0f, a2 = 0.0f, a3 = 0.0f;

  const int jw = jq * 68;      // padded word base of this j-chunk
  for (int jj = 0; jj < JCH; jj += 8) {
    const float4 rjA = *reinterpret_cast<const float4*>(&Rs[jw + jj]);
    const float4 rjB = *reinterpret_cast<const float4*>(&Rs[jw + jj + 4]);
    const float rv[8] = {rjA.x, rjA.y, rjA.z, rjA.w,
                         rjB.x, rjB.y, rjB.z, rjB.w};
#pragma unroll
    for (int u = 0; u < 8; ++u) {
      const float t = rv[u] - ri;
      // nearest-neighbor index: k = round(|t| * SCALE); |t|==0 -> k=0 -> w=0
      const float x = fmaf(fabsf(t), TBL_SCALE, 0.5f);
      const int k = (int)x;
      const unsigned tv = T[k];                    // one ds_read_b32
      const float w = __uint_as_float(tv << 16);   // exact bf16 window
      const float io = __uint_as_float(tv);        // bf16 i0e + low-bit noise
      const float dd = fabsf(t) + 1e-30f;          // keeps rsq finite at t==0
      const float r = __builtin_amdgcn_rsqf(dd);   // 1/sqrt(d)
      const float inv = r * r;                     // 1/d
      const float wi = w * inv;
      a0 = fmaf(w, inv, a0);
      a1 = fmaf(w, r, a1);
      a2 = fmaf(wi, inv, a2);
      a3 = fmaf(w, io, a3);
    }
  }

  // combine the 8 j-chunks: lanes (8k..8k+7) hold the same i
  a0 += __shfl_xor(a0, 1); a0 += __shfl_xor(a0, 2); a0 += __shfl_xor(a0, 4);
  a1 += __shfl_xor(a1, 1); a1 += __shfl_xor(a1, 2); a1 += __shfl_xor(a1, 4);
  a2 += __shfl_xor(a2, 1); a2 += __shfl_xor(a2, 2); a2 += __shfl_xor(a2, 4);
  a3 += __shfl_xor(a3, 1); a3 += __shfl_xor(a3, 2); a3 += __shfl_xor(a3, 4);

  if (jq == 0) {
    float* o = out + ((size_t)(s * NTOT + i)) * 4;
    const float nm1 = 511.0f;  // N - 1
    o[0] = fabsf(stdp[0]) * (a0 - nm1 * biasp[0]);
    o[1] = fabsf(stdp[1]) * (a1 - nm1 * biasp[1]);
    o[2] = fabsf(stdp[2]) * (a2 - nm1 * biasp[2]);
    o[3] = fabsf(stdp[3]) * (a3 - nm1 * biasp[3]);
  }
}

extern "C" void kernel_launch(void* const* d_in, const int* in_sizes, int n_in,
                              void* d_out, int out_size, void* d_ws, size_t ws_size,
                              hipStream_t stream) {
  const float* R = (const float*)d_in[0];
  const float* stdp = (const float*)d_in[1];
  const float* biasp = (const float*)d_in[2];
  float* out = (float*)d_out;

  hipLaunchKernelGGL(fill_tbl_kernel, dim3((TBL_SIZE + 255) / 256), dim3(256),
                     0, stream);
  hipLaunchKernelGGL(fmm_window_kernel, dim3(NSAMP * (NTOT / ITILE)), dim3(512),
                     0, stream, R, stdp, biasp, out);
}

// Round 8
// 72.714 us; speedup vs baseline: 1.0405x; 1.0075x over previous
//
#include <hip/hip_runtime.h>
#include <math.h>

#define NSAMP 128
#define NTOT  512            // NCELLS * NP
#define NJQ   8              // j-chunks per row
#define JCH   (NTOT / NJQ)   // 64
#define ITILE 64             // i-rows per block (512 threads = 64 i x 8 jq)

#define TBL_N    4096
#define TBL_SIZE (TBL_N + 2)     // entries 0..4097 (guard)
#define TBL_H    0.0048828125f   // 20/4096, exact in fp32
#define TBL_SCALE 204.8f         // 4096/20

typedef float v2f __attribute__((ext_vector_type(2)));

// Packed nearest-neighbor table: u32 = bf16(i0e) << 16 | bf16(w), at d_k = k*h.
// Bin 0 stores w = 0 so diagonal / exact-collision pairs contribute exactly 0
// (reference -> excluded or inf; we must stay finite & NaN-free).
__device__ unsigned g_tbl[TBL_SIZE];

// ---------------- accurate math for the table fill (cost irrelevant) -------

template <int N>
__device__ __forceinline__ float horner(float x, const float (&c)[N]) {
  float p = 0.0f;
#pragma unroll
  for (int i = 0; i < N; ++i) p = __fadd_rn(__fmul_rn(p, x), c[i]);
  return p;
}

template <int N>
__device__ __forceinline__ float chbevl(float x, const float (&c)[N]) {
  float b0 = 0.0f, b1 = 0.0f, b2 = 0.0f;
#pragma unroll
  for (int i = 0; i < N; ++i) {
    b2 = b1;
    b1 = b0;
    b0 = __fadd_rn(__fsub_rn(__fmul_rn(x, b1), b2), c[i]);
  }
  return __fmul_rn(0.5f, __fsub_rn(b0, b2));
}

__device__ __forceinline__ float erfc_xla(float x) {
  const float kErfT[7] = {
      +7.853861353153693E-5f, -8.010193625184903E-4f, +5.188327685732524E-3f,
      -2.685381193529856E-2f, +1.128358514861418E-1f, -3.761262582423300E-1f,
      +1.128379165726710E+0f};
  const float kP[9] = {
      +2.326819970068386E-2f, -1.387039388740657E-1f, +3.687424674597105E-1f,
      -5.824733027278666E-1f, +6.210004621745983E-1f, -4.944515323274145E-1f,
      +3.404879937665872E-1f, -2.741127028184656E-1f, +5.638259427386472E-1f};
  const float kR[8] = {
      -1.047766399936249E+1f, +1.297719955372516E+1f, -7.495518717768503E+0f,
      +2.921019019210786E+0f, -1.015265279202700E+0f, +4.218463358204948E-1f,
      -2.820767439740514E-1f, +5.641895067754075E-1f};

  float ax = fabsf(x);
  float x2 = __fmul_rn(x, x);
  float erf_small = __fmul_rn(x, horner(x2, kErfT));
  float erf_based = __fsub_rn(1.0f, erf_small);
  float z = expf(-x2);
  float q = __fdiv_rn(1.0f, ax);
  float y = __fmul_rn(q, q);
  float p = (ax < 2.0f) ? horner(y, kP) : horner(y, kR);
  float r = __fmul_rn(__fmul_rn(z, q), p);
  float ec = (x < 0.0f) ? __fsub_rn(2.0f, r) : r;
  return (ax < 1.0f) ? erf_based : ec;
}

__device__ __forceinline__ float i0e_xla(float x) {
  const float kA[18] = {
      -1.30002500998624804212E-8f, 6.04699502254191894932E-8f,
      -2.67079385394061173391E-7f, 1.11738753912010371815E-6f,
      -4.41673835845875056359E-6f, 1.64484480707288970893E-5f,
      -5.75419501008210370398E-5f, 1.88502885095841655729E-4f,
      -5.76375574538582365885E-4f, 1.63947561694133579842E-3f,
      -4.32430999505057594430E-3f, 1.05464603945949983183E-2f,
      -2.37374148058994688156E-2f, 4.93052842396707084878E-2f,
      -9.49010970480476444210E-2f, 1.71620901522208775349E-1f,
      -3.04682672343198398683E-1f, 6.76795274409476084995E-1f};
  const float kB[7] = {
      3.39623202570838634515E-9f, 2.26666899049817806459E-8f,
      2.04891858946906374183E-7f, 2.89137052083475648297E-6f,
      6.88975834691682398426E-5f, 3.36911647825569408990E-3f,
      8.04490411014108831608E-1f};
  float le8 = chbevl(__fsub_rn(__fmul_rn(0.5f, x), 2.0f), kA);
  float arg = __fsub_rn(__fdiv_rn(32.0f, x), 2.0f);
  float gt8 = __fdiv_rn(chbevl(arg, kB), __fsqrt_rn(x));
  return (x <= 8.0f) ? le8 : gt8;
}

__device__ __forceinline__ float window_ref(float d) {
  return 1.0f - 0.5f * erfc_xla(2.0f * d - 3.0f);
}

__device__ __forceinline__ unsigned to_bf16_rne(float x) {
  unsigned u = __float_as_uint(x);
  unsigned lsb = (u >> 16) & 1u;
  return (u + 0x7FFFu + lsb) >> 16;
}

// --------------------------- table fill kernel -----------------------------

__global__ __launch_bounds__(256) void fill_tbl_kernel() {
  int k = blockIdx.x * 256 + threadIdx.x;
  if (k >= TBL_SIZE) return;
  float d = fminf((float)k * TBL_H, 20.0f);
  float w = (k == 0) ? 0.0f : window_ref(d);   // bin 0: zero weight
  float io = (k == 0) ? 1.0f : i0e_xla(d);
  // io in HIGH 16 bits (read back with 0 ops, <=0.8% mantissa noise),
  // w in LOW 16 bits (read back exactly via << 16).
  g_tbl[k] = (to_bf16_rne(io) << 16) | to_bf16_rne(w);
}

// ------------------------------ main kernel --------------------------------

// Padded coordinate layout: chunk q (64 floats) starts at word 68*q so the 8
// per-wave float4 broadcasts land on different bank-quads.
#define RSP(j) ((j) + (((j) >> 6) << 2))
#define RSP_SIZE (NTOT + 4 * (NJQ - 1))  // 540

__global__ __launch_bounds__(512) void fmm_window_kernel(
    const float* __restrict__ R, const float* __restrict__ stdp,
    const float* __restrict__ biasp, float* __restrict__ out) {
  __shared__ unsigned T[TBL_SIZE];  // 16.4 KB
  __shared__ float Rs[RSP_SIZE];    // 2.2 KB

  const int tid = threadIdx.x;
  const int bid = blockIdx.x;
  const int s = bid >> 3;      // sample
  const int itile = bid & 7;   // 64-row tile of i

  for (int k = tid; k < TBL_SIZE; k += 512) T[k] = g_tbl[k];
  Rs[RSP(tid)] = R[s * NTOT + tid];
  __syncthreads();

  const int il = tid >> 3;     // local i (0..63)
  const int jq = tid & 7;      // j-chunk (0..7)
  const int i = itile * ITILE + il;
  const float ri = Rs[RSP(i)];
  const v2f ri2 = {ri, ri};
  const v2f S2 = {TBL_SCALE, TBL_SCALE};
  const v2f H2 = {0.5f, 0.5f};
  const v2f E2 = {1e-30f, 1e-30f};

  // packed accumulators: .x accumulates even-u pairs, .y odd-u
  v2f A0 = {0.0f, 0.0f}, A1 = {0.0f, 0.0f}, A2 = {0.0f, 0.0f},
      A3 = {0.0f, 0.0f};

  const int jw = jq * 68;      // padded word base of this j-chunk
  for (int jj = 0; jj < JCH; jj += 8) {
    const float4 rjA = *reinterpret_cast<const float4*>(&Rs[jw + jj]);
    const float4 rjB = *reinterpret_cast<const float4*>(&Rs[jw + jj + 4]);
    const v2f duo[4] = {{rjA.x, rjA.y}, {rjA.z, rjA.w},
                        {rjB.x, rjB.y}, {rjB.z, rjB.w}};
#pragma unroll
    for (int u = 0; u < 4; ++u) {
      const v2f t = duo[u] - ri2;                       // v_pk_add (neg)
      const v2f at = {fabsf(t.x), fabsf(t.y)};          // 2x v_and
      const v2f x = __builtin_elementwise_fma(at, S2, H2);  // v_pk_fma
      const int k0 = (int)x.x;                          // v_cvt
      const int k1 = (int)x.y;                          // v_cvt
      const unsigned tv0 = T[k0];                       // ds_read_b32
      const unsigned tv1 = T[k1];                       // ds_read_b32
      const v2f w = {__uint_as_float(tv0 << 16),        // 2x v_lshlrev
                     __uint_as_float(tv1 << 16)};       // exact bf16 window
      const v2f io = {__uint_as_float(tv0),             // 0 ops: bf16 i0e
                      __uint_as_float(tv1)};            //  + low-bit noise
      const v2f dd = at + E2;                           // v_pk_add (rsq finite)
      const v2f r = {__builtin_amdgcn_rsqf(dd.x),       // 2x v_rsq
                     __builtin_amdgcn_rsqf(dd.y)};
      const v2f inv = r * r;                            // v_pk_mul
      const v2f wi = w * inv;                           // v_pk_mul
      A0 = __builtin_elementwise_fma(w, inv, A0);       // v_pk_fma x4
      A1 = __builtin_elementwise_fma(w, r, A1);
      A2 = __builtin_elementwise_fma(wi, inv, A2);
      A3 = __builtin_elementwise_fma(w, io, A3);
    }
  }

  // horizontal add of the packed halves
  float a0 = A0.x + A0.y, a1 = A1.x + A1.y, a2 = A2.x + A2.y,
        a3 = A3.x + A3.y;

  // combine the 8 j-chunks: lanes (8k..8k+7) hold the same i
  a0 += __shfl_xor(a0, 1); a0 += __shfl_xor(a0, 2); a0 += __shfl_xor(a0, 4);
  a1 += __shfl_xor(a1, 1); a1 += __shfl_xor(a1, 2); a1 += __shfl_xor(a1, 4);
  a2 += __shfl_xor(a2, 1); a2 += __shfl_xor(a2, 2); a2 += __shfl_xor(a2, 4);
  a3 += __shfl_xor(a3, 1); a3 += __shfl_xor(a3, 2); a3 += __shfl_xor(a3, 4);

  if (jq == 0) {
    float* o = out + ((size_t)(s * NTOT + i)) * 4;
    const float nm1 = 511.0f;  // N - 1
    o[0] = fabsf(stdp[0]) * (a0 - nm1 * biasp[0]);
    o[1] = fabsf(stdp[1]) * (a1 - nm1 * biasp[1]);
    o[2] = fabsf(stdp[2]) * (a2 - nm1 * biasp[2]);
    o[3] = fabsf(stdp[3]) * (a3 - nm1 * biasp[3]);
  }
}

extern "C" void kernel_launch(void* const* d_in, const int* in_sizes, int n_in,
                              void* d_out, int out_size, void* d_ws, size_t ws_size,
                              hipStream_t stream) {
  const float* R = (const float*)d_in[0];
  const float* stdp = (const float*)d_in[1];
  const float* biasp = (const float*)d_in[2];
  float* out = (float*)d_out;

  hipLaunchKernelGGL(fill_tbl_kernel, dim3((TBL_SIZE + 255) / 256), dim3(256),
                     0, stream);
  hipLaunchKernelGGL(fmm_window_kernel, dim3(NSAMP * (NTOT / ITILE)), dim3(512),
                     0, stream, R, stdp, biasp, out);
}